// Round 3
// baseline (195.542 us; speedup 1.0000x reference)
//
#include <hip/hip_runtime.h>

#define TPB 1024

// Shapes (all fp32): x(8,14,14,32,16) a(8,14,14,32) W(288,32,16) beta_u(32) beta_a(32)
// out (fp32): p_out(8,6,6,32,16)=147456 then a_out(8,6,6,32)=9216.
// One block per output position (288). 1024 thr = 32 n-slices x 32 c, 9 n per thread.
__global__ __launch_bounds__(TPB) void convcaps_kernel(
    const float* __restrict__ xg,
    const float* __restrict__ ag,
    const float* __restrict__ wg,
    const float* __restrict__ bu,
    const float* __restrict__ ba,
    float* __restrict__ outp)
{
    __shared__ __align__(16) float pose_s[4608];   // [288][16]
    __shared__ float a_s[288];
    __shared__ __align__(16) float scratch[8448];  // 8 slots x 32 c x 33 (16 m + 16 v + pad)
    __shared__ float rsum_part[256];               // 8 slots x 32 c
    __shared__ float A_tab[512];                   // i2s = 0.5/sigma          [c][p]
    __shared__ float B_tab[512];                   // 2*mu*i2s = mu/sigma      [c][p]
    __shared__ float Kc_tab[32];                   // 0.5*sum log sig - log a_out + sum mu^2*i2s

    const int tid = threadIdx.x;
    const int pos = blockIdx.x;
    const int bb  = pos / 36;
    const int rem = pos % 36;
    const int yy  = rem / 6;
    const int xx  = rem % 6;

    // ---- stage pose + a_in into LDS ----
    for (int i = tid; i < 4608; i += TPB) {
        const int wi = i >> 9, off = i & 511;
        const int kh = wi / 3, kw = wi % 3;
        pose_s[i] = xg[(size_t)((((bb * 14) + (2 * yy + kh)) * 14 + (2 * xx + kw)) * 32) * 16 + off];
    }
    if (tid < 288) {
        const int wi = tid >> 5, bi = tid & 31;
        const int kh = wi / 3, kw = wi % 3;
        a_s[tid] = ag[(size_t)(((bb * 14) + (2 * yy + kh)) * 14 + (2 * xx + kw)) * 32 + bi];
    }
    __syncthreads();

    const int c    = tid & 31;   // capsule-out index
    const int s    = tid >> 5;   // n-slice 0..31 (9 n each)
    const int lane = tid & 63;
    const int wv   = tid >> 6;   // wave 0..15
    const float4* wp = (const float4*)wg;

    for (int it = 0; it < 3; ++it) {
        // hoisted per-c routing state: dist = sum_p v*(v*A - B) + (const folded into Kc)
        float A_c[16], B_c[16], Kc = 0.f;
        if (it > 0) {
            #pragma unroll
            for (int p = 0; p < 16; ++p) {
                A_c[p] = A_tab[c * 16 + p];
                B_c[p] = B_tab[c * 16 + p];
            }
            Kc = Kc_tab[c];
        }
        float macc[16], vacc[16], rs = 0.f;
        #pragma unroll
        for (int p = 0; p < 16; ++p) { macc[p] = 0.f; vacc[p] = 0.f; }

        // ---- fused E+M pass, 9 n per thread, W software-pipelined ----
        int wb = ((s * 9) * 32 + c) * 4;
        float4 cw0 = wp[wb], cw1 = wp[wb + 1], cw2 = wp[wb + 2], cw3 = wp[wb + 3];
        #pragma unroll 1
        for (int k = 0; k < 9; ++k) {
            const int n = s * 9 + k;
            const float4* pp = (const float4*)&pose_s[n << 4];
            float4 q0 = pp[0], q1 = pp[1], q2 = pp[2], q3 = pp[3];
            // prefetch next k's weights (overlaps L2 latency with softmax/accum below)
            float4 nw0, nw1, nw2, nw3;
            if (k < 8) {
                const int nb = wb + 128;
                nw0 = wp[nb]; nw1 = wp[nb + 1]; nw2 = wp[nb + 2]; nw3 = wp[nb + 3];
            }
            float pf[16] = {q0.x,q0.y,q0.z,q0.w, q1.x,q1.y,q1.z,q1.w,
                            q2.x,q2.y,q2.z,q2.w, q3.x,q3.y,q3.z,q3.w};
            float wf[16] = {cw0.x,cw0.y,cw0.z,cw0.w, cw1.x,cw1.y,cw1.z,cw1.w,
                            cw2.x,cw2.y,cw2.z,cw2.w, cw3.x,cw3.y,cw3.z,cw3.w};
            // v = pose(4x4) @ W(4x4), flattened p = i*4+l
            float v[16];
            #pragma unroll
            for (int i = 0; i < 4; ++i)
                #pragma unroll
                for (int l = 0; l < 4; ++l)
                    v[i*4+l] = pf[i*4+0] * wf[0*4+l] + pf[i*4+1] * wf[1*4+l]
                             + pf[i*4+2] * wf[2*4+l] + pf[i*4+3] * wf[3*4+l];
            float r;
            if (it == 0) {
                r = a_s[n] * 0.03125f;  // (1/C) * a_in
            } else {
                float t = 0.f;
                #pragma unroll
                for (int p = 0; p < 16; ++p)
                    t = fmaf(fmaf(v[p], A_c[p], -B_c[p]), v[p], t);
                float lnap = -t - Kc;
                // softmax over the 32 c-lanes (half-wave group, lockstep in k)
                float m = lnap;
                #pragma unroll
                for (int msk = 16; msk >= 1; msk >>= 1) m = fmaxf(m, __shfl_xor(m, msk));
                float e = __expf(lnap - m);
                float sum = e;
                #pragma unroll
                for (int msk = 16; msk >= 1; msk >>= 1) sum += __shfl_xor(sum, msk);
                r = e / sum;
            }
            rs += r;
            #pragma unroll
            for (int p = 0; p < 16; ++p) {
                float rv = r * v[p];
                macc[p] = fmaf(r, v[p], macc[p]);    // sum r*v
                vacc[p] = fmaf(rv, v[p], vacc[p]);   // sum r*v^2
            }
            wb += 128;
            if (k < 8) { cw0 = nw0; cw1 = nw1; cw2 = nw2; cw3 = nw3; }
        }

        // ---- reduce 32 slices: shfl pair, then two-round LDS tree over 16 waves ----
        #pragma unroll
        for (int p = 0; p < 16; ++p) {
            macc[p] += __shfl_xor(macc[p], 32);
            vacc[p] += __shfl_xor(vacc[p], 32);
        }
        rs += __shfl_xor(rs, 32);
        if (lane < 32 && wv >= 8) {  // c = lane
            const int base = ((wv - 8) * 32 + lane) * 33;
            #pragma unroll
            for (int p = 0; p < 16; ++p) {
                scratch[base + p]      = macc[p];
                scratch[base + 16 + p] = vacc[p];
            }
            rsum_part[(wv - 8) * 32 + lane] = rs;
        }
        __syncthreads();
        if (lane < 32 && wv < 8) {
            const int base = (wv * 32 + lane) * 33;
            #pragma unroll
            for (int p = 0; p < 16; ++p) {
                scratch[base + p]      += macc[p];
                scratch[base + 16 + p] += vacc[p];
            }
            rsum_part[wv * 32 + lane] += rs;
        }
        __syncthreads();

        // ---- finalize: first 512 threads = (fc, fp) cover 32x16 (c,p) ----
        if (tid < 512) {
            const int fc = tid >> 4, fp = tid & 15;
            float ms = 0.f, vs = 0.f, rsc = 0.f;
            #pragma unroll
            for (int w = 0; w < 8; ++w) {
                ms  += scratch[(w * 32 + fc) * 33 + fp];
                vs  += scratch[(w * 32 + fc) * 33 + 16 + fp];
                rsc += rsum_part[w * 32 + fc];
            }
            const float inv = 1.f / (rsc + 1e-6f);
            const float S   = rsc * inv;
            const float mu  = ms * inv;
            const float sig = vs * inv - mu * mu * (2.f - S) + 1e-6f;
            const float ia  = 0.5f / sig;              // i2s
            const float lg  = __logf(sig);
            const float cs  = mu * mu * ia;            // const term, folded into Kc
            float lgs = lg, ccs = cs;  // reduce over the 16 p-lanes sharing fc
            #pragma unroll
            for (int msk = 8; msk >= 1; msk >>= 1) {
                lgs += __shfl_xor(lgs, msk);
                ccs += __shfl_xor(ccs, msk);
            }
            const float buv  = bu[fc];
            const float bav  = ba[fc];
            const float cost = rsc * (16.f * buv + 0.5f * lgs);
            const float ao   = 1.f / (1.f + __expf(-0.001f * (bav - cost)));

            A_tab[fc * 16 + fp] = ia;
            B_tab[fc * 16 + fp] = 2.f * mu * ia;
            if (fp == 0) Kc_tab[fc] = 0.5f * lgs - __logf(ao) + ccs;

            if (it == 2) {
                outp[(size_t)pos * 512 + tid] = mu;   // p_out: pos*512 + c*16 + p
                if (fp == 0) outp[147456 + (size_t)pos * 32 + fc] = ao;
            }
        }
        __syncthreads();  // tabs visible before next iteration's hoisted reads
    }
}

extern "C" void kernel_launch(void* const* d_in, const int* in_sizes, int n_in,
                              void* d_out, int out_size, void* d_ws, size_t ws_size,
                              hipStream_t stream) {
    (void)in_sizes; (void)n_in; (void)out_size; (void)d_ws; (void)ws_size;
    const float* x  = (const float*)d_in[0];
    const float* a  = (const float*)d_in[1];
    const float* w  = (const float*)d_in[2];
    const float* bu = (const float*)d_in[3];
    const float* ba = (const float*)d_in[4];
    float* out = (float*)d_out;
    convcaps_kernel<<<dim3(288), dim3(TPB), 0, stream>>>(x, a, w, bu, ba, out);
}

// Round 4
// 161.417 us; speedup vs baseline: 1.2114x; 1.2114x over previous
//
#include <hip/hip_runtime.h>

#define TPB 512

// Shapes (all fp32): x(8,14,14,32,16) a(8,14,14,32) W(288,32,16) beta_u(32) beta_a(32)
// out (fp32): p_out(8,6,6,32,16)=147456 then a_out(8,6,6,32)=9216.
// One block per output position (288). 512 thr = 16 n-slices x 32 c, 18 n per thread,
// processed as 9 independent PAIRS for ILP (interleaved softmax shuffle chains).
// __launch_bounds__(512,4): VGPR cap 128 — keeps 2 blocks/CU co-resident on straggler CUs.
__global__ __launch_bounds__(TPB, 4) void convcaps_kernel(
    const float* __restrict__ xg,
    const float* __restrict__ ag,
    const float* __restrict__ wg,
    const float* __restrict__ bu,
    const float* __restrict__ ba,
    float* __restrict__ outp)
{
    __shared__ __align__(16) float pose_s[4608];   // [288][16]
    __shared__ float a_s[288];
    __shared__ __align__(16) float scratch[8448];  // 8 waves x 32 c x 33 (16 m + 16 v + pad)
    __shared__ float rsum_part[256];               // 8 waves x 32 c
    __shared__ float A_tab[512];                   // 0.5/sigma                [c][p]
    __shared__ float B_tab[512];                   // mu/sigma = 2*mu*A       [c][p]
    __shared__ float Kc_tab[32];                   // sum mu^2*A + 0.5*sum log sig - log a_out

    const int tid = threadIdx.x;
    const int pos = blockIdx.x;
    const int bb  = pos / 36;
    const int rem = pos % 36;
    const int yy  = rem / 6;
    const int xx  = rem % 6;

    // ---- stage pose + a_in into LDS ----
    #pragma unroll
    for (int wi = 0; wi < 9; ++wi) {
        const int kh = wi / 3, kw = wi % 3;
        const float* src =
            xg + (size_t)((((bb * 14) + (2 * yy + kh)) * 14 + (2 * xx + kw)) * 32) * 16;
        pose_s[wi * 512 + tid] = src[tid];
    }
    if (tid < 288) {
        const int wi = tid >> 5, bi = tid & 31;
        const int kh = wi / 3, kw = wi % 3;
        a_s[tid] = ag[(size_t)(((bb * 14) + (2 * yy + kh)) * 14 + (2 * xx + kw)) * 32 + bi];
    }
    __syncthreads();

    const int c    = tid & 31;   // capsule-out index
    const int s    = tid >> 5;   // n-slice 0..15 (18 n each)
    const int lane = tid & 63;
    const int wv   = tid >> 6;   // wave 0..7
    const float4* wp = (const float4*)wg;

    for (int it = 0; it < 3; ++it) {
        // hoisted per-c routing state: dist = sum_p v*(v*A - B), const folded into Kc
        float A_c[16], B_c[16], Kc = 0.f;
        if (it > 0) {
            #pragma unroll
            for (int p = 0; p < 16; ++p) {
                A_c[p] = A_tab[c * 16 + p];
                B_c[p] = B_tab[c * 16 + p];
            }
            Kc = Kc_tab[c];
        }
        float macc[16], vacc[16], rs = 0.f;
        #pragma unroll
        for (int p = 0; p < 16; ++p) { macc[p] = 0.f; vacc[p] = 0.f; }

        // ---- fused E+M pass: 9 pairs of n (18 total), chains interleaved ----
        #pragma unroll 1
        for (int k = 0; k < 9; ++k) {
            const int n0 = s * 18 + 2 * k;
            const int n1 = n0 + 1;
            const float4* pp0 = (const float4*)&pose_s[n0 << 4];
            const float4* pp1 = (const float4*)&pose_s[n1 << 4];
            const float4* wq0 = wp + (size_t)(n0 * 32 + c) * 4;
            const float4* wq1 = wp + (size_t)(n1 * 32 + c) * 4;

            float v0[16], v1[16];
            {   // v = pose(4x4) @ W(4x4), row-streamed to limit live regs
                float4 w0 = wq0[0], w1 = wq0[1], w2 = wq0[2], w3 = wq0[3];
                float wf[16] = {w0.x,w0.y,w0.z,w0.w, w1.x,w1.y,w1.z,w1.w,
                                w2.x,w2.y,w2.z,w2.w, w3.x,w3.y,w3.z,w3.w};
                #pragma unroll
                for (int i = 0; i < 4; ++i) {
                    float4 q = pp0[i];
                    #pragma unroll
                    for (int l = 0; l < 4; ++l)
                        v0[i*4+l] = fmaf(q.x, wf[l], fmaf(q.y, wf[4+l],
                                     fmaf(q.z, wf[8+l], q.w * wf[12+l])));
                }
            }
            {
                float4 w0 = wq1[0], w1 = wq1[1], w2 = wq1[2], w3 = wq1[3];
                float wf[16] = {w0.x,w0.y,w0.z,w0.w, w1.x,w1.y,w1.z,w1.w,
                                w2.x,w2.y,w2.z,w2.w, w3.x,w3.y,w3.z,w3.w};
                #pragma unroll
                for (int i = 0; i < 4; ++i) {
                    float4 q = pp1[i];
                    #pragma unroll
                    for (int l = 0; l < 4; ++l)
                        v1[i*4+l] = fmaf(q.x, wf[l], fmaf(q.y, wf[4+l],
                                     fmaf(q.z, wf[8+l], q.w * wf[12+l])));
                }
            }

            float r0, r1;
            if (it == 0) {
                r0 = a_s[n0] * 0.03125f;   // (1/C) * a_in — c-uniform, no softmax
                r1 = a_s[n1] * 0.03125f;
            } else {
                float t0 = 0.f, t1 = 0.f;
                #pragma unroll
                for (int p = 0; p < 16; ++p) {
                    t0 = fmaf(fmaf(v0[p], A_c[p], -B_c[p]), v0[p], t0);
                    t1 = fmaf(fmaf(v1[p], A_c[p], -B_c[p]), v1[p], t1);
                }
                float l0 = -t0 - Kc, l1 = -t1 - Kc;
                // softmax over the 32 c-lanes; two chains interleaved for ILP
                float m0 = l0, m1 = l1;
                #pragma unroll
                for (int msk = 16; msk >= 1; msk >>= 1) {
                    m0 = fmaxf(m0, __shfl_xor(m0, msk));
                    m1 = fmaxf(m1, __shfl_xor(m1, msk));
                }
                float e0 = __expf(l0 - m0), e1 = __expf(l1 - m1);
                float s0 = e0, s1 = e1;
                #pragma unroll
                for (int msk = 16; msk >= 1; msk >>= 1) {
                    s0 += __shfl_xor(s0, msk);
                    s1 += __shfl_xor(s1, msk);
                }
                r0 = e0 / s0;
                r1 = e1 / s1;
            }
            rs += r0 + r1;
            #pragma unroll
            for (int p = 0; p < 16; ++p) {
                macc[p] = fmaf(r0, v0[p], fmaf(r1, v1[p], macc[p]));
                vacc[p] = fmaf(r0 * v0[p], v0[p], fmaf(r1 * v1[p], v1[p], vacc[p]));
            }
        }

        // ---- reduce the 16 n-slices: shfl pairs, then LDS across 8 waves ----
        #pragma unroll
        for (int p = 0; p < 16; ++p) {
            macc[p] += __shfl_xor(macc[p], 32);
            vacc[p] += __shfl_xor(vacc[p], 32);
        }
        rs += __shfl_xor(rs, 32);
        if (lane < 32) {  // c = lane
            const int base = (wv * 32 + lane) * 33;  // +33 stride: conflict-free
            #pragma unroll
            for (int p = 0; p < 16; ++p) {
                scratch[base + p]      = macc[p];
                scratch[base + 16 + p] = vacc[p];
            }
            rsum_part[wv * 32 + lane] = rs;
        }
        __syncthreads();

        // ---- finalize: thread = (fc, fp) covers all 32x16 (c,p) ----
        const int fc = tid >> 4, fp = tid & 15;
        float ms = 0.f, vs = 0.f, rsc = 0.f;
        #pragma unroll
        for (int w = 0; w < 8; ++w) {
            ms  += scratch[(w * 32 + fc) * 33 + fp];
            vs  += scratch[(w * 32 + fc) * 33 + 16 + fp];
            rsc += rsum_part[w * 32 + fc];
        }
        const float inv = 1.f / (rsc + 1e-6f);
        const float S   = rsc * inv;
        const float mu  = ms * inv;
        const float sig = vs * inv - mu * mu * (2.f - S) + 1e-6f;
        const float ia  = 0.5f / sig;
        const float lg  = __logf(sig);
        const float cs  = mu * mu * ia;            // const term, folded into Kc
        float lgs = lg, ccs = cs;  // reduce over the 16 p-lanes sharing fc
        #pragma unroll
        for (int msk = 8; msk >= 1; msk >>= 1) {
            lgs += __shfl_xor(lgs, msk);
            ccs += __shfl_xor(ccs, msk);
        }
        const float buv  = bu[fc];
        const float bav  = ba[fc];
        const float cost = rsc * (16.f * buv + 0.5f * lgs);
        const float ao   = 1.f / (1.f + __expf(-0.001f * (bav - cost)));

        A_tab[fc * 16 + fp] = ia;
        B_tab[fc * 16 + fp] = 2.f * mu * ia;
        if (fp == 0) Kc_tab[fc] = 0.5f * lgs - __logf(ao) + ccs;

        if (it == 2) {
            outp[(size_t)pos * 512 + tid] = mu;   // p_out: pos*512 + c*16 + p
            if (fp == 0) outp[147456 + (size_t)pos * 32 + fc] = ao;
        }
        __syncthreads();  // tabs visible before next iteration's hoisted reads
    }
}

extern "C" void kernel_launch(void* const* d_in, const int* in_sizes, int n_in,
                              void* d_out, int out_size, void* d_ws, size_t ws_size,
                              hipStream_t stream) {
    (void)in_sizes; (void)n_in; (void)out_size; (void)d_ws; (void)ws_size;
    const float* x  = (const float*)d_in[0];
    const float* a  = (const float*)d_in[1];
    const float* w  = (const float*)d_in[2];
    const float* bu = (const float*)d_in[3];
    const float* ba = (const float*)d_in[4];
    float* out = (float*)d_out;
    convcaps_kernel<<<dim3(288), dim3(TPB), 0, stream>>>(x, a, w, bu, ba, out);
}